// Round 2
// baseline (373.389 us; speedup 1.0000x reference)
//
#include <hip/hip_runtime.h>
#include <hip/hip_bf16.h>

typedef __bf16 bf16;
typedef __bf16 bf16x8 __attribute__((ext_vector_type(8)));
typedef float  f32x4  __attribute__((ext_vector_type(4)));

// ---------------------------------------------------------------------------
// NNConv, atomic-free restructure:
//   Round-1 rocprof showed the agg atomics are the wall (WRITE_SIZE 75MB vs
//   3.2MB agg array => memory-side RMW per edge; occupancy fix was neutral).
//   New plan: build a dst-sorted CSR permutation once (hist+scan+scatter),
//   edge kernels write msg[] in dst-sorted order (streaming stores, NO
//   atomics), aggregation is a contiguous segment-sum per node.
// Pooling: batch sorted -> per-graph binary search + LDS reduction.
// ---------------------------------------------------------------------------

// ---------------- CSR build ------------------------------------------------

__global__ void hist_deg(const int* __restrict__ eidx, int* __restrict__ deg, int E)
{
    int e = blockIdx.x * blockDim.x + threadIdx.x;
    if (e < E) atomicAdd(&deg[eidx[E + e]], 1);
}

// per-256-chunk exclusive scan; chunk totals to bsum
__global__ void scan_blocks(const int* __restrict__ deg, int* __restrict__ part,
                            int* __restrict__ bsum, int N)
{
    __shared__ int sm[256];
    const int t = threadIdx.x;
    const int i = blockIdx.x * 256 + t;
    int v = (i < N) ? deg[i] : 0;
    sm[t] = v;
    __syncthreads();
#pragma unroll
    for (int ofs = 1; ofs < 256; ofs <<= 1) {
        int add = (t >= ofs) ? sm[t - ofs] : 0;
        __syncthreads();
        sm[t] += add;
        __syncthreads();
    }
    if (i < N) part[i] = sm[t] - v;          // exclusive
    if (t == 255) bsum[blockIdx.x] = sm[255];
}

// single-block exclusive scan of chunk totals (nb <= 256)
__global__ void scan_top(const int* __restrict__ bsum, int* __restrict__ boff, int nb)
{
    __shared__ int sm[256];
    const int t = threadIdx.x;
    int v = (t < nb) ? bsum[t] : 0;
    sm[t] = v;
    __syncthreads();
#pragma unroll
    for (int ofs = 1; ofs < 256; ofs <<= 1) {
        int add = (t >= ofs) ? sm[t - ofs] : 0;
        __syncthreads();
        sm[t] += add;
        __syncthreads();
    }
    if (t < nb) boff[t] = sm[t] - v;
}

__global__ void scan_fix(int* __restrict__ rowptr, int* __restrict__ cursor,
                         const int* __restrict__ boff, int N, int E)
{
    int i = blockIdx.x * 256 + threadIdx.x;
    if (i < N) {
        int r = rowptr[i] + boff[blockIdx.x];
        rowptr[i] = r;
        cursor[i] = r;
    }
    if (i == N) rowptr[N] = E;
}

// scatter (src, edge_attr) into dst-sorted slots
__global__ void scatter_edges(const int* __restrict__ eidx, const float* __restrict__ ea,
                              int* __restrict__ cursor, int2* __restrict__ edat, int E)
{
    int e = blockIdx.x * blockDim.x + threadIdx.x;
    if (e >= E) return;
    int d = eidx[E + e];
    int j = atomicAdd(&cursor[d], 1);
    edat[j] = make_int2(eidx[e], __float_as_int(ea[e]));
}

// ---------------- layer kernels -------------------------------------------

__global__ void node_pre1(const float* __restrict__ x,
                          const float* __restrict__ b_e1b,
                          const float* __restrict__ root1,
                          const float* __restrict__ bias1,
                          float* __restrict__ d1, float* __restrict__ r1, int N)
{
    int t = blockIdx.x * blockDim.x + threadIdx.x;
    int v = t >> 4, o = t & 15;
    if (v >= N) return;
    float dacc = 0.f, racc = 0.f;
#pragma unroll
    for (int i = 0; i < 8; ++i) {
        float xv = x[v * 8 + i];
        dacc += xv * b_e1b[i * 16 + o];
        racc += xv * root1[i * 16 + o];
    }
    d1[v * 16 + o] = dacc;
    r1[v * 16 + o] = racc + bias1[o];
}

// Edge kernel layer 1: 16 edges/wave-tile, K=128 via 4x mfma_16x16x32_bf16.
// Edges pre-sorted by dst; writes msg[] streaming (no atomics).
__global__ void edge_l1(const float* __restrict__ x,
                        const int2*  __restrict__ edat,
                        const float* __restrict__ W_e1a, const float* __restrict__ b_e1a,
                        const float* __restrict__ W_e1b,
                        const float* __restrict__ d1,
                        float* __restrict__ msg, int ntiles)
{
    const int lane = threadIdx.x & 63;
    const int m = lane & 15;          // A row (edge in tile) / C col (out chan)
    const int q = lane >> 4;          // quad
    const int wave   = blockIdx.x * (blockDim.x >> 6) + (threadIdx.x >> 6);
    const int nwaves = gridDim.x * (blockDim.x >> 6);

    // B fragments: B[k][n] = W_e1b[(i*16+n)*16 + j], j=c*4+q, i=t
    bf16x8 bfrag[4];
#pragma unroll
    for (int c = 0; c < 4; ++c)
#pragma unroll
        for (int t = 0; t < 8; ++t)
            bfrag[c][t] = (bf16)W_e1b[(t * 16 + m) * 16 + (c * 4 + q)];

    float wa[4], bb[4];
#pragma unroll
    for (int c = 0; c < 4; ++c) { wa[c] = W_e1a[c * 4 + q]; bb[c] = b_e1a[c * 4 + q]; }

    int tile = wave;
    if (tile >= ntiles) return;

    int2 ed = edat[tile * 16 + m];

    while (tile < ntiles) {
        const int ntile = tile + nwaves;
        int2 ed_nx = ed;
        if (ntile < ntiles) ed_nx = edat[ntile * 16 + m];

        const int s = ed.x;
        const float t_ea = __int_as_float(ed.y);

        const float4* xp = (const float4*)(x + (size_t)s * 8);
        float4 x0 = xp[0], x1 = xp[1];

        // d1[src] rides as MFMA C-in; rows r=q*4+reg held by this lane
        f32x4 acc;
#pragma unroll
        for (int reg = 0; reg < 4; ++reg) {
            int s_r = __shfl(s, q * 4 + reg, 64);
            acc[reg] = d1[s_r * 16 + m];
        }

        float he[4];
#pragma unroll
        for (int c = 0; c < 4; ++c) {
            float h = wa[c] * t_ea + bb[c];
            he[c] = h > 0.f ? h : 0.f;
        }

        float xv[8] = {x0.x, x0.y, x0.z, x0.w, x1.x, x1.y, x1.z, x1.w};
#pragma unroll
        for (int c = 0; c < 4; ++c) {
            bf16x8 afrag;
#pragma unroll
            for (int t = 0; t < 8; ++t) afrag[t] = (bf16)(he[c] * xv[t]);
            acc = __builtin_amdgcn_mfma_f32_16x16x32_bf16(afrag, bfrag[c], acc, 0, 0, 0);
        }

        // streaming store: wave writes msg[tile*256 .. +256) contiguous
        float* mrow = msg + (size_t)tile * 256;
#pragma unroll
        for (int reg = 0; reg < 4; ++reg)
            mrow[(q * 4 + reg) * 16 + m] = acc[reg];

        ed = ed_nx; tile = ntile;
    }
}

// Aggregate layer 1 (contiguous segment-sum) + finalize + layer-2 precompute.
__global__ void agg_fin1(const float* __restrict__ msg, const int* __restrict__ rowptr,
                         const float* __restrict__ r1,
                         const float* __restrict__ b_e2b, const float* __restrict__ root2,
                         const float* __restrict__ bias2,
                         float* __restrict__ h1, float* __restrict__ d2,
                         float* __restrict__ r2, int N)
{
    int t = blockIdx.x * blockDim.x + threadIdx.x;
    int v = t >> 4, o = t & 15;
    if (v >= N) return;
    int j0 = rowptr[v], j1 = rowptr[v + 1];
    float acc = 0.f;
    for (int j = j0; j < j1; ++j)
        acc += msg[(size_t)j * 16 + o];
    float c = (float)(j1 - j0); c = c > 1.f ? c : 1.f;
    float h = acc / c + r1[v * 16 + o];
    h = h > 0.f ? h : 0.f;
    h1[v * 16 + o] = h;
    float dacc = 0.f, racc = 0.f;
#pragma unroll
    for (int i = 0; i < 16; ++i) {
        float hv = __shfl(h, i, 16);
        dacc += hv * b_e2b[i * 16 + o];
        racc += hv * root2[i * 16 + o];
    }
    d2[v * 16 + o] = dacc;
    r2[v * 16 + o] = racc + bias2[o];
}

// Edge kernel layer 2: K=256 via 8x mfma_16x16x32_bf16. Streaming msg stores.
__global__ void edge_l2(const float* __restrict__ h1g,
                        const int2*  __restrict__ edat,
                        const float* __restrict__ W_e2a, const float* __restrict__ b_e2a,
                        const float* __restrict__ W_e2b,
                        const float* __restrict__ d2,
                        float* __restrict__ msg, int ntiles)
{
    const int lane = threadIdx.x & 63;
    const int m = lane & 15;
    const int q = lane >> 4;
    const int qh = q >> 1;            // j = 2c + qh
    const int ql = q & 1;             // i = ql*8 + t
    const int wave   = blockIdx.x * (blockDim.x >> 6) + (threadIdx.x >> 6);
    const int nwaves = gridDim.x * (blockDim.x >> 6);

    bf16x8 bfrag[8];
#pragma unroll
    for (int c = 0; c < 8; ++c) {
        int j = c * 2 + qh;
#pragma unroll
        for (int t = 0; t < 8; ++t) {
            int i = ql * 8 + t;
            bfrag[c][t] = (bf16)W_e2b[(i * 16 + m) * 16 + j];
        }
    }

    float wa[8], bb[8];
#pragma unroll
    for (int c = 0; c < 8; ++c) { wa[c] = W_e2a[c * 2 + qh]; bb[c] = b_e2a[c * 2 + qh]; }

    int tile = wave;
    if (tile >= ntiles) return;

    int2 ed = edat[tile * 16 + m];

    while (tile < ntiles) {
        const int ntile = tile + nwaves;
        int2 ed_nx = ed;
        if (ntile < ntiles) ed_nx = edat[ntile * 16 + m];

        const int s = ed.x;
        const float t_ea = __int_as_float(ed.y);

        const float4* hp = (const float4*)(h1g + (size_t)s * 16 + ql * 8);
        float4 h0 = hp[0], h1v = hp[1];

        f32x4 acc;
#pragma unroll
        for (int reg = 0; reg < 4; ++reg) {
            int s_r = __shfl(s, q * 4 + reg, 64);
            acc[reg] = d2[s_r * 16 + m];
        }

        float he[8];
#pragma unroll
        for (int c = 0; c < 8; ++c) {
            float h = wa[c] * t_ea + bb[c];
            he[c] = h > 0.f ? h : 0.f;
        }

        float hv[8] = {h0.x, h0.y, h0.z, h0.w, h1v.x, h1v.y, h1v.z, h1v.w};
#pragma unroll
        for (int c = 0; c < 8; ++c) {
            bf16x8 afrag;
#pragma unroll
            for (int t = 0; t < 8; ++t) afrag[t] = (bf16)(he[c] * hv[t]);
            acc = __builtin_amdgcn_mfma_f32_16x16x32_bf16(afrag, bfrag[c], acc, 0, 0, 0);
        }

        float* mrow = msg + (size_t)tile * 256;
#pragma unroll
        for (int reg = 0; reg < 4; ++reg)
            mrow[(q * 4 + reg) * 16 + m] = acc[reg];

        ed = ed_nx; tile = ntile;
    }
}

// Aggregate layer 2 + finalize outputs (no atomics).
__global__ void agg_fin2(const float* __restrict__ msg, const int* __restrict__ rowptr,
                         const float* __restrict__ r2, const int* __restrict__ batch,
                         float* __restrict__ out_h, float* __restrict__ out_b, int N)
{
    int t = blockIdx.x * blockDim.x + threadIdx.x;
    int v = t >> 4, o = t & 15;
    if (v >= N) return;
    int j0 = rowptr[v], j1 = rowptr[v + 1];
    float acc = 0.f;
    for (int j = j0; j < j1; ++j)
        acc += msg[(size_t)j * 16 + o];
    float c = (float)(j1 - j0); c = c > 1.f ? c : 1.f;
    float h = acc / c + r2[v * 16 + o];
    h = h > 0.f ? h : 0.f;
    out_h[v * 16 + o] = h;
    if (o == 0) out_b[v] = (float)batch[v];
}

// Global mean pool: batch sorted -> one block per graph, binary search + LDS.
__global__ void pool_seg(const float* __restrict__ h, const int* __restrict__ batch,
                         float* __restrict__ out_g, int N)
{
    const int b = blockIdx.x;
    int lo = 0, hi = N;
    while (lo < hi) { int mid = (lo + hi) >> 1; if (batch[mid] < b) lo = mid + 1; else hi = mid; }
    const int start = lo;
    hi = N;
    while (lo < hi) { int mid = (lo + hi) >> 1; if (batch[mid] < b + 1) lo = mid + 1; else hi = mid; }
    const int end = lo;

    const int ch = threadIdx.x & 15, grp = threadIdx.x >> 4;
    float acc = 0.f;
    for (int v = start + grp; v < end; v += 16)
        acc += h[(size_t)v * 16 + ch];

    __shared__ float red[256];
    red[threadIdx.x] = acc;
    __syncthreads();
#pragma unroll
    for (int s = 128; s >= 16; s >>= 1) {
        if (threadIdx.x < s) red[threadIdx.x] += red[threadIdx.x + s];
        __syncthreads();
    }
    if (threadIdx.x < 16) {
        float c = (float)(end - start); c = c > 1.f ? c : 1.f;
        out_g[b * 16 + threadIdx.x] = red[threadIdx.x] / c;
    }
}

extern "C" void kernel_launch(void* const* d_in, const int* in_sizes, int n_in,
                              void* d_out, int out_size, void* d_ws, size_t ws_size,
                              hipStream_t stream)
{
    const float* x     = (const float*)d_in[0];
    const float* ea    = (const float*)d_in[1];
    const float* W_e1a = (const float*)d_in[2];
    const float* b_e1a = (const float*)d_in[3];
    const float* W_e1b = (const float*)d_in[4];
    const float* b_e1b = (const float*)d_in[5];
    const float* root1 = (const float*)d_in[6];
    const float* bias1 = (const float*)d_in[7];
    const float* W_e2a = (const float*)d_in[8];
    const float* b_e2a = (const float*)d_in[9];
    const float* W_e2b = (const float*)d_in[10];
    const float* b_e2b = (const float*)d_in[11];
    const float* root2 = (const float*)d_in[12];
    const float* bias2 = (const float*)d_in[13];
    const int*   eidx  = (const int*)d_in[14];
    const int*   batch = (const int*)d_in[15];

    const int E  = in_sizes[1];       // 800000
    const int N  = in_sizes[15];      // 50000
    const int Bg = (out_size - N * 16 - N) / 16;   // 64

    auto align16 = [](size_t v) { return (v + 15) & ~(size_t)15; };

    char* ws = (char*)d_ws;
    size_t off = 0;
    int*   deg    = (int*)(ws + off);  off = align16(off + (size_t)N * 4);
    size_t zero_bytes = off;                     // only deg needs zeroing
    int*   rowptr = (int*)(ws + off);  off = align16(off + (size_t)(N + 1) * 4);
    int*   cursor = (int*)(ws + off);  off = align16(off + (size_t)N * 4);
    int*   bsum   = (int*)(ws + off);  off = align16(off + 256 * 4);
    int*   boff   = (int*)(ws + off);  off = align16(off + 256 * 4);
    int2*  edat   = (int2*)(ws + off); off = align16(off + (size_t)E * 8);
    float* msg    = (float*)(ws + off); off = align16(off + (size_t)E * 16 * 4);
    float* d1 = (float*)(ws + off); off = align16(off + (size_t)N * 16 * 4);
    float* r1 = (float*)(ws + off); off = align16(off + (size_t)N * 16 * 4);
    float* h1 = (float*)(ws + off); off = align16(off + (size_t)N * 16 * 4);
    float* d2 = (float*)(ws + off); off = align16(off + (size_t)N * 16 * 4);
    float* r2 = (float*)(ws + off); off = align16(off + (size_t)N * 16 * 4);

    hipMemsetAsync(d_ws, 0, zero_bytes, stream);

    const int nodeBlocks = (N * 16 + 255) / 256;
    const int edgeThreadBlocks = (E + 255) / 256;
    const int scanBlocks = (N + 255) / 256;       // 196 (must be <= 256)
    const int ntiles = E / 16;
    const int edgeBlocks = 2048;

    // CSR build
    hist_deg<<<edgeThreadBlocks, 256, 0, stream>>>(eidx, deg, E);
    scan_blocks<<<scanBlocks, 256, 0, stream>>>(deg, rowptr, bsum, N);
    scan_top<<<1, 256, 0, stream>>>(bsum, boff, scanBlocks);
    scan_fix<<<scanBlocks, 256, 0, stream>>>(rowptr, cursor, boff, N, E);
    scatter_edges<<<edgeThreadBlocks, 256, 0, stream>>>(eidx, ea, cursor, edat, E);

    // layer 1
    node_pre1<<<nodeBlocks, 256, 0, stream>>>(x, b_e1b, root1, bias1, d1, r1, N);
    edge_l1<<<edgeBlocks, 256, 0, stream>>>(x, edat, W_e1a, b_e1a, W_e1b, d1,
                                            msg, ntiles);
    agg_fin1<<<nodeBlocks, 256, 0, stream>>>(msg, rowptr, r1, b_e2b, root2, bias2,
                                             h1, d2, r2, N);

    // layer 2
    edge_l2<<<edgeBlocks, 256, 0, stream>>>(h1, edat, W_e2a, b_e2a, W_e2b, d2,
                                            msg, ntiles);

    float* out_h = (float*)d_out;
    float* out_g = out_h + (size_t)N * 16;
    float* out_b = out_g + (size_t)Bg * 16;
    agg_fin2<<<nodeBlocks, 256, 0, stream>>>(msg, rowptr, r2, batch, out_h,
                                             out_b, N);
    pool_seg<<<Bg, 256, 0, stream>>>(out_h, batch, out_g, N);
}